// Round 5
// baseline (523.402 us; speedup 1.0000x reference)
//
#include <hip/hip_runtime.h>

typedef unsigned short ushort_t;
typedef unsigned char u8;
typedef short bf16x8 __attribute__((ext_vector_type(8)));
typedef float f32x4 __attribute__((ext_vector_type(4)));

#define T_DIM 4
#define B_DIM 32
#define C_DIM 512
#define N_DIM 256

__device__ __forceinline__ float bf2f(ushort_t u) {
  union { unsigned int i; float f; } x;
  x.i = ((unsigned int)u) << 16;
  return x.f;
}
__device__ __forceinline__ ushort_t f2bf(float f) {
  unsigned int u = __float_as_uint(f);
  u = (u + 0x7FFFu + ((u >> 16) & 1u)) >> 16;
  return (ushort_t)u;
}

// async global->LDS DMA, 16B per lane, lane i lands at ldsbase + i*16
__device__ __forceinline__ void gload16(const void* g, void* l) {
  __builtin_amdgcn_global_load_lds(
      (const __attribute__((address_space(1))) unsigned int*)g,
      (__attribute__((address_space(3))) unsigned int*)l, 16, 0, 0);
}

// ---------------------------------------------------------------------------
// K0: split fp32 weights into 3 bf16 planes (hi, mid, lo). W ~= hi+mid+lo.
// ---------------------------------------------------------------------------
__global__ __launch_bounds__(256) void k0_split(
    const float* __restrict__ Wq, const float* __restrict__ Wk,
    const float* __restrict__ Wv, const float* __restrict__ Wp,
    ushort_t* __restrict__ Sqkv, ushort_t* __restrict__ Sp)
{
  int gid = blockIdx.x * 256 + threadIdx.x;   // [0, 131072)
  int w = gid >> 15;
  int off = (gid & 32767) * 8;
  const float* src = (w == 0) ? Wq : ((w == 1) ? Wk : ((w == 2) ? Wv : Wp));
  ushort_t* dst = (w < 3) ? (Sqkv + (size_t)w * 3 * 262144) : Sp;
  float wv[8];
  *(float4*)&wv[0] = *(const float4*)(src + off);
  *(float4*)&wv[4] = *(const float4*)(src + off + 4);
  ushort_t hi[8], mi[8], lo[8];
#pragma unroll
  for (int i = 0; i < 8; i++) {
    float f = wv[i];
    ushort_t h = f2bf(f);  float r  = f - bf2f(h);
    ushort_t m = f2bf(r);  float r2 = r - bf2f(m);
    ushort_t l = f2bf(r2);
    hi[i] = h; mi[i] = m; lo[i] = l;
  }
  *(uint4*)(dst + off)              = *(uint4*)&hi[0];
  *(uint4*)(dst + 262144 + off)     = *(uint4*)&mi[0];
  *(uint4*)(dst + 2 * 262144 + off) = *(uint4*)&lo[0];
}

// ---------------------------------------------------------------------------
// K1: shortcut LIF on x [T,B,C,N] (fp32) -> spikes transposed xsT8 [T,B,N,C] u8
// ---------------------------------------------------------------------------
__global__ __launch_bounds__(256) void k1_shortcut_lif(
    const float* __restrict__ x, u8* __restrict__ xsT8)
{
  const int n0 = blockIdx.x * 64;
  const int c0 = blockIdx.y * 64;
  const int b  = blockIdx.z;
  __shared__ u8 sm[64][80];
  const int tid = threadIdx.x;
  const int r  = tid >> 2;
  const int j0 = (tid & 3) * 16;
  float v[16];
#pragma unroll
  for (int i = 0; i < 16; i++) v[i] = 0.f;
  for (int t = 0; t < T_DIM; t++) {
    const float* xp = x + ((((size_t)t * B_DIM + b) * C_DIM) + c0 + r) * N_DIM + n0 + j0;
    float xv[16];
    *(float4*)&xv[0]  = *(const float4*)xp;
    *(float4*)&xv[4]  = *(const float4*)(xp + 4);
    *(float4*)&xv[8]  = *(const float4*)(xp + 8);
    *(float4*)&xv[12] = *(const float4*)(xp + 12);
    __syncthreads();
#pragma unroll
    for (int i = 0; i < 16; i++) {
      float nv = v[i] + (xv[i] - v[i]) * 0.5f;
      bool s = (nv >= 1.0f);
      v[i] = s ? 0.f : nv;
      sm[j0 + i][r] = s ? (u8)1 : (u8)0;
    }
    __syncthreads();
    union { uint4 u; u8 b[16]; } ov;
#pragma unroll
    for (int i = 0; i < 16; i++) ov.b[i] = sm[r][j0 + i];
    u8* op = xsT8 + ((((size_t)t * B_DIM + b) * N_DIM) + n0 + r) * C_DIM + c0 + j0;
    *(uint4*)op = ov.u;
  }
}

// ---------------------------------------------------------------------------
// K2: QKV conv1x1 + BN + LIF. 512 threads (8 waves), 64m x 256n block tile,
// wave tile 16m x 128n (acc[8]).
// m97-style depth-1 pipeline, 40 KB LDS (2 buffers) so all 768 blocks are
// resident (3 blocks/CU, capacity 4): STAGE(s+1) issued at loop top (in
// flight under the full compute phase), vmcnt(0)+s_barrier at loop bottom.
// A (3 bf16 planes) and B (spike u8) staged via async global_load_lds with
// PRE-SWIZZLED global sources (LDS dest linear), read with matching XOR:
//   A: slot16' = slot16 ^ ((row>>1)&3)            (2-way residual = free)
//   B: half16' = half16 ^ ((row>>2 ^ row>>3)&1)   (2-way residual = free;
//      16B-granular XOR keeps each lane's DMA contiguous)
// B kept as u8 in LDS; expanded to bf16 at frag-read via v_perm_b32 + mul.
// XCD remap: lin%8 == b%8; all blocks resident -> L2 window per step is
// small (A-slice + B-slice ~300KB/XCD).
//    q -> qs8[t,b,c,n] u8 ; k -> ks8[t,b,c,n] u8
//    v -> vout[t,b,h,n,d] fp32 0/1 via full-line float4 stores.
// ---------------------------------------------------------------------------
__global__ __launch_bounds__(512, 4) void k2_qkv(
    const u8* __restrict__ xsT8, const ushort_t* __restrict__ Sqkv,
    const float* __restrict__ qsc, const float* __restrict__ qbi,
    const float* __restrict__ ksc, const float* __restrict__ kbi,
    const float* __restrict__ vsc, const float* __restrict__ vbi,
    u8* __restrict__ qs8, u8* __restrict__ ks8, float* __restrict__ vout)
{
  const int lin = blockIdx.x + blockIdx.y * 24;        // 0..767
  const int b   = (lin & 7) | (((lin >> 3) & 3) << 3); // XCD = lin%8 = b%8
  const int mt  = lin >> 5;                            // 0..23
  const int branch = mt >> 3;         // 0=q 1=k 2=v
  const int mloc = (mt & 7) * 64;     // within branch's 512
  const ushort_t* Ws = Sqkv + (size_t)branch * 3 * 262144;
  const float* scp = (branch == 0) ? qsc : ((branch == 1) ? ksc : vsc);
  const float* bip = (branch == 0) ? qbi : ((branch == 1) ? kbi : vbi);

  __shared__ alignas(16) ushort_t As[2][3][64][32];   // 24 KB, linear dest
  __shared__ alignas(16) u8 Bs8[2][256][32];          // 16 KB, linear dest

  const int tid  = threadIdx.x;
  const int lane = tid & 63;
  const int wave = tid >> 6;
  const int wrow = (wave >> 1) * 16;   // m strip (16 rows)
  const int wcol = (wave & 1) * 128;   // n half (128 cols)
  const int frow = lane & 15;
  const int fsl  = lane >> 4;          // 8-elem slot 0..3

  const u8* Bb0 = xsT8 + (size_t)b * N_DIM * C_DIM;

  // staging chunks: 12 A-chunks (1KB = plane p, 16-row group q) over 8 waves,
  // 8 B-chunks (1KB = 32 n-rows). waves 0-3: A{wave}, A{8+wave}, B{4+wave};
  // waves 4-7: A{wave}, B{wave-4}.
  const int a0p = wave >> 2, a0q = wave & 3;
  const int arl = lane >> 2;                              // row within 16
  const int acl = (((lane & 3) ^ ((arl >> 1) & 3)) * 8);  // swizzled 16B slot (ushort units)
  const int brl = lane >> 1;                              // row within 32
  const int bcl = (((lane & 1) ^ ((brl >> 2) & 1) ^ ((brl >> 3) & 1)) * 16); // swizzled 16B half (bytes)
  const int cbx = (wave < 4) ? (4 + wave) : (wave - 4);

#define K2_STAGE(s_) {                                                                     \
    const int ss_ = (s_);                                                                  \
    const int t_ = ss_ >> 4; const int kb_ = (ss_ & 15) * 32; const int bf_ = ss_ & 1;     \
    gload16(Ws + (size_t)a0p * 262144 + (size_t)(mloc + a0q * 16 + arl) * 512 + kb_ + acl, \
            &As[bf_][a0p][a0q * 16][0]);                                                   \
    if (wave < 4)                                                                          \
      gload16(Ws + 2 * 262144 + (size_t)(mloc + wave * 16 + arl) * 512 + kb_ + acl,        \
              &As[bf_][2][wave * 16][0]);                                                  \
    gload16(Bb0 + (size_t)t_ * (B_DIM * N_DIM * C_DIM) + (size_t)(cbx * 32 + brl) * 512 + kb_ + bcl, \
            &Bs8[bf_][cbx * 32][0]);                                                       \
  }

  f32x4 acc[8];
  float vst[32];
#pragma unroll
  for (int i = 0; i < 32; i++) vst[i] = 0.f;
#pragma unroll
  for (int j = 0; j < 8; j++) acc[j] = (f32x4){0.f, 0.f, 0.f, 0.f};

  // preload BN scale/bias for this thread's 4 c-rows (constant across t)
  const int crow0 = (lane >> 4) * 4;
  const int cn    = lane & 15;
  float sc4[4], bi4[4];
#pragma unroll
  for (int r = 0; r < 4; r++) {
    int c = mloc + wrow + crow0 + r;
    sc4[r] = scp[c]; bi4[r] = bip[c];
  }

  K2_STAGE(0);
  asm volatile("s_waitcnt vmcnt(0)" ::: "memory");
  __builtin_amdgcn_s_barrier();
  __builtin_amdgcn_sched_barrier(0);

  for (int s = 0; s < 64; s++) {
    const int cur = s & 1;
    if (s < 63) K2_STAGE(s + 1);   // async into buf^1; lands during compute

    bf16x8 af[3];
    const int ar = wrow + frow;
    const int asw = (fsl ^ ((ar >> 1) & 3)) * 8;   // matches source pre-swizzle
#pragma unroll
    for (int p = 0; p < 3; p++) af[p] = *(const bf16x8*)&As[cur][p][ar][asw];

#pragma unroll
    for (int j = 0; j < 8; j++) {
      const int row = wcol + j * 16 + frow;
      const int bx  = ((row >> 2) ^ (row >> 3)) & 1;
      const int bsw = (((fsl >> 1) ^ bx) << 4) + ((fsl & 1) << 3); // matches source pre-swizzle
      uint2 raw = *(const uint2*)&Bs8[cur][row][bsw];
      union { bf16x8 v; unsigned int u[4]; } bu;
      bu.u[0] = __builtin_amdgcn_perm(0u, raw.x, 0x05010400u) * 0x3F80u;
      bu.u[1] = __builtin_amdgcn_perm(0u, raw.x, 0x07030602u) * 0x3F80u;
      bu.u[2] = __builtin_amdgcn_perm(0u, raw.y, 0x05010400u) * 0x3F80u;
      bu.u[3] = __builtin_amdgcn_perm(0u, raw.y, 0x07030602u) * 0x3F80u;
#pragma unroll
      for (int p = 0; p < 3; p++)
        acc[j] = __builtin_amdgcn_mfma_f32_16x16x32_bf16(af[p], bu.v, acc[j], 0, 0, 0);
    }

    if ((s & 15) == 15) {
      // epilogue for t = s>>4
      const int t = s >> 4;
      const size_t tb = (size_t)t * B_DIM + b;
      if (branch < 2) {
        u8* dst = (branch == 0) ? qs8 : ks8;
#pragma unroll
        for (int r = 0; r < 4; r++) {
          const int c = mloc + wrow + crow0 + r;
#pragma unroll
          for (int j = 0; j < 8; j++) {
            const int n = wcol + j * 16 + cn;
            float y = acc[j][r] * sc4[r] + bi4[r];
            const int vi = j * 4 + r;
            float v = vst[vi];
            v = v + (y - v) * 0.5f;
            bool sp = (v >= 1.0f);
            vst[vi] = sp ? 0.f : v;
            dst[(tb * C_DIM + c) * N_DIM + n] = sp ? (u8)1 : (u8)0;
          }
        }
      } else {
        const int hv = mloc >> 6;
        const int d0 = wrow + crow0;
#pragma unroll
        for (int j = 0; j < 8; j++) {
          const int n = wcol + j * 16 + cn;
          float ov[4];
#pragma unroll
          for (int r = 0; r < 4; r++) {
            float y = acc[j][r] * sc4[r] + bi4[r];
            const int vi = j * 4 + r;
            float v = vst[vi];
            v = v + (y - v) * 0.5f;
            bool sp = (v >= 1.0f);
            vst[vi] = sp ? 0.f : v;
            ov[r] = sp ? 1.0f : 0.0f;
          }
          *(float4*)(vout + ((tb * 8 + hv) * N_DIM + n) * 64 + d0) =
              make_float4(ov[0], ov[1], ov[2], ov[3]);
        }
      }
#pragma unroll
      for (int j = 0; j < 8; j++) acc[j] = (f32x4){0.f, 0.f, 0.f, 0.f};
    }

    // stage(s+1) + any epilogue stores must retire before next step reads/
    // overwrites; all waves must be past their reads of buf cur^1.
    asm volatile("s_waitcnt vmcnt(0)" ::: "memory");
    __builtin_amdgcn_s_barrier();
    __builtin_amdgcn_sched_barrier(0);
  }
#undef K2_STAGE
}

// ---------------------------------------------------------------------------
// K3: attn[ch,b,h,d,e] = (1/16) * sum_{t,n} k[d,(t,n)] * v[(t,n),e]
// ---------------------------------------------------------------------------
__global__ __launch_bounds__(256) void k3_attn(
    const u8* __restrict__ ks8, const float* __restrict__ vsp,
    float* __restrict__ attn)
{
  const int h  = blockIdx.x;
  const int b  = blockIdx.y;
  const int ch = blockIdx.z;
  __shared__ u8 KtT[64][80];
  __shared__ u8 Vt[64][80];
  const int tid = threadIdx.x;
  const int d0 = (tid >> 4) * 4;
  const int e0 = (tid & 15) * 4;
  float a[16];
#pragma unroll
  for (int i = 0; i < 16; i++) a[i] = 0.f;

  for (int tt = 0; tt < 2; tt++) {
    int t = ch * 2 + tt;
    for (int n0 = 0; n0 < 256; n0 += 64) {
      __syncthreads();
      {
        int d  = tid >> 2;
        int s0 = (tid & 3) * 16;
        union { uint4 u; u8 bvec[16]; } kb;
        kb.u = *(const uint4*)(ks8 + ((((size_t)t * B_DIM + b) * C_DIM) + h * 64 + d) * N_DIM + n0 + s0);
#pragma unroll
        for (int i = 0; i < 16; i++) KtT[s0 + i][d] = kb.bvec[i];
      }
      {
        const float* vb = vsp + ((((size_t)t * B_DIM + b) * 8 + h) * N_DIM + n0) * 64;
#pragma unroll
        for (int u = 0; u < 4; u++) {
          int chunk = tid + u * 256;
          int row = chunk >> 4;
          int eo  = (chunk & 15) * 4;
          float4 v4 = *(const float4*)(vb + (size_t)row * 64 + eo);
          Vt[row][eo + 0] = (u8)(v4.x != 0.f);
          Vt[row][eo + 1] = (u8)(v4.y != 0.f);
          Vt[row][eo + 2] = (u8)(v4.z != 0.f);
          Vt[row][eo + 3] = (u8)(v4.w != 0.f);
        }
      }
      __syncthreads();
      for (int s = 0; s < 64; s++) {
        uchar4 kb = *(const uchar4*)&KtT[s][d0];
        float kv[4] = { (float)kb.x, (float)kb.y, (float)kb.z, (float)kb.w };
        uchar4 vr = *(const uchar4*)&Vt[s][e0];
        float vv[4] = { (float)vr.x, (float)vr.y, (float)vr.z, (float)vr.w };
#pragma unroll
        for (int i = 0; i < 4; i++)
#pragma unroll
          for (int j = 0; j < 4; j++) a[i * 4 + j] += kv[i] * vv[j];
      }
    }
  }
  float* ap = attn + ((((size_t)ch * B_DIM + b) * 8 + h) * 64 + d0) * 64 + e0;
#pragma unroll
  for (int i = 0; i < 4; i++)
#pragma unroll
    for (int j = 0; j < 4; j++)
      ap[i * 64 + j] = a[i * 4 + j] * 0.0625f;
}

// ---------------------------------------------------------------------------
// K4: out[e,n] = sum_d attn[d,e]*q[d,n], attn-LIF(0.5) -> x2sT8[t,b,n,c] u8.
// n-chunk split across grid.z for 4x parallelism; vst[16] per thread.
// ---------------------------------------------------------------------------
__global__ __launch_bounds__(256) void k4_out_lif(
    const u8* __restrict__ qs8, const float* __restrict__ attn,
    u8* __restrict__ x2sT8)
{
  const int h  = blockIdx.x;
  const int b  = blockIdx.y;
  const int nc = blockIdx.z;   // 0..3
  __shared__ float At[64][68];
  __shared__ u8 Qt[64][80];
  const int tid = threadIdx.x;
  const int e0 = (tid >> 4) * 4;
  const int n0 = (tid & 15) * 4;
  float vst[16];
#pragma unroll
  for (int i = 0; i < 16; i++) vst[i] = 0.f;

  for (int t = 0; t < T_DIM; t++) {
    if ((t & 1) == 0) {
      __syncthreads();
      const float* ap = attn + ((((size_t)(t >> 1) * B_DIM + b) * 8) + h) * 4096;
      int dr = tid >> 2;
      int co = (tid & 3) * 16;
#pragma unroll
      for (int u = 0; u < 4; u++)
        *(float4*)&At[dr][co + u * 4] = *(const float4*)(ap + dr * 64 + co + u * 4);
    }
    __syncthreads();
    {
      int d  = tid >> 2;
      int so = (tid & 3) * 16;
      *(uint4*)&Qt[d][so] =
        *(const uint4*)(qs8 + ((((size_t)t * B_DIM + b) * C_DIM) + h * 64 + d) * N_DIM + nc * 64 + so);
    }
    __syncthreads();
    float acc[16];
#pragma unroll
    for (int i = 0; i < 16; i++) acc[i] = 0.f;
    for (int d = 0; d < 64; d++) {
      float4 av = *(const float4*)&At[d][e0];
      float avv[4] = { av.x, av.y, av.z, av.w };
      uchar4 qr = *(const uchar4*)&Qt[d][n0];
      float qv[4] = { (float)qr.x, (float)qr.y, (float)qr.z, (float)qr.w };
#pragma unroll
      for (int i = 0; i < 4; i++)
#pragma unroll
        for (int j = 0; j < 4; j++) acc[i * 4 + j] += avv[i] * qv[j];
    }
#pragma unroll
    for (int j = 0; j < 4; j++) {
      u8 sv[4];
#pragma unroll
      for (int i = 0; i < 4; i++) {
        int vi = i * 4 + j;
        float y = acc[i * 4 + j];
        float nv = vst[vi] + (y - vst[vi]) * 0.5f;
        bool s = (nv >= 0.5f);
        vst[vi] = s ? 0.f : nv;
        sv[i] = s ? (u8)1 : (u8)0;
      }
      int n = nc * 64 + n0 + j;
      u8* op = x2sT8 + ((((size_t)t * B_DIM + b) * N_DIM) + n) * C_DIM + h * 64 + e0;
      *(uchar4*)op = make_uchar4(sv[0], sv[1], sv[2], sv[3]);
    }
  }
}

// ---------------------------------------------------------------------------
// K5: proj conv1x1 (+bp)*scale+bias + residual -> out0 fp32. Same engine as
// K2: 40 KB LDS depth-1 pipeline (1024 blocks = 4/CU = full residency),
// DMA staging with pre-swizzled sources. Grid (tb, mt): XCD = tb%8 ->
// per-XCD working set B 2MB + A 1.5MB < 4MB L2.
// ---------------------------------------------------------------------------
__global__ __launch_bounds__(512, 4) void k5_proj(
    const u8* __restrict__ x2sT8, const ushort_t* __restrict__ Sp,
    const float* __restrict__ bp, const float* __restrict__ psc,
    const float* __restrict__ pbi,
    const float* __restrict__ x, float* __restrict__ out0)
{
  const int tb = blockIdx.x;   // 0..127 (fast dim -> XCD = tb%8)
  const int mt = blockIdx.y;   // 0..7
  const int mloc = mt * 64;

  __shared__ alignas(16) ushort_t As[2][3][64][32];
  __shared__ alignas(16) u8 Bs8[2][256][32];

  const int tid  = threadIdx.x;
  const int lane = tid & 63;
  const int wave = tid >> 6;
  const int wrow = (wave >> 1) * 16;
  const int wcol = (wave & 1) * 128;
  const int frow = lane & 15;
  const int fsl  = lane >> 4;

  const u8* Bb = x2sT8 + (size_t)tb * N_DIM * C_DIM;

  const int a0p = wave >> 2, a0q = wave & 3;
  const int arl = lane >> 2;
  const int acl = (((lane & 3) ^ ((arl >> 1) & 3)) * 8);
  const int brl = lane >> 1;
  const int bcl = (((lane & 1) ^ ((brl >> 2) & 1) ^ ((brl >> 3) & 1)) * 16);
  const int cbx = (wave < 4) ? (4 + wave) : (wave - 4);

#define K5_STAGE(s_) {                                                                     \
    const int ss_ = (s_); const int kb_ = ss_ * 32; const int bf_ = ss_ & 1;               \
    gload16(Sp + (size_t)a0p * 262144 + (size_t)(mloc + a0q * 16 + arl) * 512 + kb_ + acl, \
            &As[bf_][a0p][a0q * 16][0]);                                                   \
    if (wave < 4)                                                                          \
      gload16(Sp + 2 * 262144 + (size_t)(mloc + wave * 16 + arl) * 512 + kb_ + acl,        \
              &As[bf_][2][wave * 16][0]);                                                  \
    gload16(Bb + (size_t)(cbx * 32 + brl) * 512 + kb_ + bcl, &Bs8[bf_][cbx * 32][0]);      \
  }

  f32x4 acc[8];
#pragma unroll
  for (int j = 0; j < 8; j++) acc[j] = (f32x4){0.f, 0.f, 0.f, 0.f};

  K5_STAGE(0);
  asm volatile("s_waitcnt vmcnt(0)" ::: "memory");
  __builtin_amdgcn_s_barrier();
  __builtin_amdgcn_sched_barrier(0);

  for (int s = 0; s < 16; s++) {
    const int cur = s & 1;
    if (s < 15) K5_STAGE(s + 1);

    bf16x8 af[3];
    const int ar = wrow + frow;
    const int asw = (fsl ^ ((ar >> 1) & 3)) * 8;
#pragma unroll
    for (int p = 0; p < 3; p++) af[p] = *(const bf16x8*)&As[cur][p][ar][asw];

#pragma unroll
    for (int j = 0; j < 8; j++) {
      const int row = wcol + j * 16 + frow;
      const int bx  = ((row >> 2) ^ (row >> 3)) & 1;
      const int bsw = (((fsl >> 1) ^ bx) << 4) + ((fsl & 1) << 3);
      uint2 raw = *(const uint2*)&Bs8[cur][row][bsw];
      union { bf16x8 v; unsigned int u[4]; } bu;
      bu.u[0] = __builtin_amdgcn_perm(0u, raw.x, 0x05010400u) * 0x3F80u;
      bu.u[1] = __builtin_amdgcn_perm(0u, raw.x, 0x07030602u) * 0x3F80u;
      bu.u[2] = __builtin_amdgcn_perm(0u, raw.y, 0x05010400u) * 0x3F80u;
      bu.u[3] = __builtin_amdgcn_perm(0u, raw.y, 0x07030602u) * 0x3F80u;
#pragma unroll
      for (int p = 0; p < 3; p++)
        acc[j] = __builtin_amdgcn_mfma_f32_16x16x32_bf16(af[p], bu.v, acc[j], 0, 0, 0);
    }

    asm volatile("s_waitcnt vmcnt(0)" ::: "memory");
    __builtin_amdgcn_s_barrier();
    __builtin_amdgcn_sched_barrier(0);
  }

  const int crow0 = (lane >> 4) * 4;
  const int cn    = lane & 15;
#pragma unroll
  for (int r = 0; r < 4; r++) {
    const int c = mloc + wrow + crow0 + r;
    const float scf = psc[c];
    const float bif = pbi[c];
    const float bpf = bp[c];
#pragma unroll
    for (int j = 0; j < 8; j++) {
      const int n = wcol + j * 16 + cn;
      const size_t idx = ((size_t)tb * C_DIM + c) * N_DIM + n;
      out0[idx] = (acc[j][r] + bpf) * scf + bif + x[idx];
    }
  }
#undef K5_STAGE
}

// ---------------------------------------------------------------------------
// fp32 problem. d_out = 33,554,432 floats: out0 [0,16.7M), out1 [16.7M,33.5M).
// Scratch in out0 byte region (dead until K5 overwrites it):
//   o0+0    xsT8 16MB [K1->K2]  (aliased by attn 8MB [K3->K4])
//   o0+16M  qs8 16MB [K2->K4] ; o0+32M ks8 16MB [K2->K3]
//   o0+48M  Sqkv split 4.5MB [K0->K2]
// d_ws: x2sT8 16MB [K4->K5]; +16M Sp split 1.5MB [K0->K5].
// ---------------------------------------------------------------------------
extern "C" void kernel_launch(void* const* d_in, const int* in_sizes, int n_in,
                              void* d_out, int out_size, void* d_ws, size_t ws_size,
                              hipStream_t stream) {
  const float* x   = (const float*)d_in[0];
  const float* Wq  = (const float*)d_in[1];
  const float* qsc = (const float*)d_in[2];
  const float* qbi = (const float*)d_in[3];
  const float* Wk  = (const float*)d_in[4];
  const float* ksc = (const float*)d_in[5];
  const float* kbi = (const float*)d_in[6];
  const float* Wv  = (const float*)d_in[7];
  const float* vsc = (const float*)d_in[8];
  const float* vbi = (const float*)d_in[9];
  const float* Wp  = (const float*)d_in[10];
  const float* bp  = (const float*)d_in[11];
  const float* psc = (const float*)d_in[12];
  const float* pbi = (const float*)d_in[13];

  float* out0 = (float*)d_out;
  float* out1 = out0 + 16777216;

  const size_t M16 = 16u * 1024u * 1024u;
  char* o0 = (char*)d_out;
  char* ws = (char*)d_ws;

  u8*       xsT8  = (u8*)(o0);
  u8*       qs8   = (u8*)(o0 + M16);
  u8*       ks8   = (u8*)(o0 + 2 * M16);
  ushort_t* Sqkv  = (ushort_t*)(o0 + 3 * M16);
  float*    attn  = (float*)(o0);
  u8*       x2sT8 = (u8*)(ws);
  ushort_t* Sp    = (ushort_t*)(ws + M16);

  hipLaunchKernelGGL(k0_split,        dim3(512),        dim3(256), 0, stream,
                     Wq, Wk, Wv, Wp, Sqkv, Sp);
  hipLaunchKernelGGL(k1_shortcut_lif, dim3(4, 8, 32),   dim3(256), 0, stream, x, xsT8);
  hipLaunchKernelGGL(k2_qkv,          dim3(24, 32),     dim3(512), 0, stream,
                     xsT8, Sqkv, qsc, qbi, ksc, kbi, vsc, vbi, qs8, ks8, out1);
  hipLaunchKernelGGL(k3_attn,         dim3(8, 32, 2),   dim3(256), 0, stream, ks8, out1, attn);
  hipLaunchKernelGGL(k4_out_lif,      dim3(8, 32, 4),   dim3(256), 0, stream, qs8, attn, x2sT8);
  hipLaunchKernelGGL(k5_proj,         dim3(128, 8),     dim3(512), 0, stream,
                     x2sT8, Sp, bp, psc, pbi, x, out0);
}

// Round 6
// 467.406 us; speedup vs baseline: 1.1198x; 1.1198x over previous
//
#include <hip/hip_runtime.h>

typedef unsigned short ushort_t;
typedef unsigned char u8;
typedef short bf16x8 __attribute__((ext_vector_type(8)));
typedef float f32x4 __attribute__((ext_vector_type(4)));

#define T_DIM 4
#define B_DIM 32
#define C_DIM 512
#define N_DIM 256

__device__ __forceinline__ float bf2f(ushort_t u) {
  union { unsigned int i; float f; } x;
  x.i = ((unsigned int)u) << 16;
  return x.f;
}
__device__ __forceinline__ ushort_t f2bf(float f) {
  unsigned int u = __float_as_uint(f);
  u = (u + 0x7FFFu + ((u >> 16) & 1u)) >> 16;
  return (ushort_t)u;
}

// async global->LDS DMA, 16B per lane, lane i lands at ldsbase + i*16
__device__ __forceinline__ void gload16(const void* g, void* l) {
  __builtin_amdgcn_global_load_lds(
      (const __attribute__((address_space(1))) unsigned int*)g,
      (__attribute__((address_space(3))) unsigned int*)l, 16, 0, 0);
}

// ---------------------------------------------------------------------------
// K0: split fp32 weights into 3 bf16 planes (hi, mid, lo). W ~= hi+mid+lo.
// (K2/K5 consume only hi+mid: 2-plane split error ~8e-7 rms is below the
// fp32 accumulation-order noise both kernel and reference already carry.)
// ---------------------------------------------------------------------------
__global__ __launch_bounds__(256) void k0_split(
    const float* __restrict__ Wq, const float* __restrict__ Wk,
    const float* __restrict__ Wv, const float* __restrict__ Wp,
    ushort_t* __restrict__ Sqkv, ushort_t* __restrict__ Sp)
{
  int gid = blockIdx.x * 256 + threadIdx.x;   // [0, 131072)
  int w = gid >> 15;
  int off = (gid & 32767) * 8;
  const float* src = (w == 0) ? Wq : ((w == 1) ? Wk : ((w == 2) ? Wv : Wp));
  ushort_t* dst = (w < 3) ? (Sqkv + (size_t)w * 3 * 262144) : Sp;
  float wv[8];
  *(float4*)&wv[0] = *(const float4*)(src + off);
  *(float4*)&wv[4] = *(const float4*)(src + off + 4);
  ushort_t hi[8], mi[8], lo[8];
#pragma unroll
  for (int i = 0; i < 8; i++) {
    float f = wv[i];
    ushort_t h = f2bf(f);  float r  = f - bf2f(h);
    ushort_t m = f2bf(r);  float r2 = r - bf2f(m);
    ushort_t l = f2bf(r2);
    hi[i] = h; mi[i] = m; lo[i] = l;
  }
  *(uint4*)(dst + off)              = *(uint4*)&hi[0];
  *(uint4*)(dst + 262144 + off)     = *(uint4*)&mi[0];
  *(uint4*)(dst + 2 * 262144 + off) = *(uint4*)&lo[0];
}

// ---------------------------------------------------------------------------
// K1: shortcut LIF on x [T,B,C,N] (fp32) -> spikes transposed xsT8 [T,B,N,C] u8
// ---------------------------------------------------------------------------
__global__ __launch_bounds__(256) void k1_shortcut_lif(
    const float* __restrict__ x, u8* __restrict__ xsT8)
{
  const int n0 = blockIdx.x * 64;
  const int c0 = blockIdx.y * 64;
  const int b  = blockIdx.z;
  __shared__ u8 sm[64][80];
  const int tid = threadIdx.x;
  const int r  = tid >> 2;
  const int j0 = (tid & 3) * 16;
  float v[16];
#pragma unroll
  for (int i = 0; i < 16; i++) v[i] = 0.f;
  for (int t = 0; t < T_DIM; t++) {
    const float* xp = x + ((((size_t)t * B_DIM + b) * C_DIM) + c0 + r) * N_DIM + n0 + j0;
    float xv[16];
    *(float4*)&xv[0]  = *(const float4*)xp;
    *(float4*)&xv[4]  = *(const float4*)(xp + 4);
    *(float4*)&xv[8]  = *(const float4*)(xp + 8);
    *(float4*)&xv[12] = *(const float4*)(xp + 12);
    __syncthreads();
#pragma unroll
    for (int i = 0; i < 16; i++) {
      float nv = v[i] + (xv[i] - v[i]) * 0.5f;
      bool s = (nv >= 1.0f);
      v[i] = s ? 0.f : nv;
      sm[j0 + i][r] = s ? (u8)1 : (u8)0;
    }
    __syncthreads();
    union { uint4 u; u8 b[16]; } ov;
#pragma unroll
    for (int i = 0; i < 16; i++) ov.b[i] = sm[r][j0 + i];
    u8* op = xsT8 + ((((size_t)t * B_DIM + b) * N_DIM) + n0 + r) * C_DIM + c0 + j0;
    *(uint4*)op = ov.u;
  }
}

// ---------------------------------------------------------------------------
// K2: QKV conv1x1 + BN + LIF. 512 threads (8 waves), 64m x 256n block tile,
// wave tile 16m x 128n (acc[8]). TWO bf16 weight planes (hi+mid).
// Depth-2 counted-vmcnt pipeline (r3 structure, measured best): 4 rotating
// LDS buffers (64 KB), ONE raw s_barrier per k-step, steady-state
// s_waitcnt vmcnt(4) (= 2 stages x 2 loads/wave in flight, never 0).
// Staging: uniform 2 gload16 per wave per stage (1 A chunk + 1 B chunk).
// Pre-swizzled global sources (LDS dest linear), matching XOR on read.
// XCD remap: lin%8 == b%8.
//    q -> qs8[t,b,c,n] u8 ; k -> ks8[t,b,c,n] u8
//    v -> vout[t,b,h,n,d] fp32 0/1 (out1)  AND  vs8 u8 copy for K3.
// ---------------------------------------------------------------------------
__global__ __launch_bounds__(512, 4) void k2_qkv(
    const u8* __restrict__ xsT8, const ushort_t* __restrict__ Sqkv,
    const float* __restrict__ qsc, const float* __restrict__ qbi,
    const float* __restrict__ ksc, const float* __restrict__ kbi,
    const float* __restrict__ vsc, const float* __restrict__ vbi,
    u8* __restrict__ qs8, u8* __restrict__ ks8, float* __restrict__ vout,
    u8* __restrict__ vs8)
{
  const int lin = blockIdx.x + blockIdx.y * 24;        // 0..767
  const int b   = (lin & 7) | (((lin >> 3) & 3) << 3); // XCD = lin%8 = b%8
  const int mt  = lin >> 5;                            // 0..23
  const int branch = mt >> 3;         // 0=q 1=k 2=v
  const int mloc = (mt & 7) * 64;     // within branch's 512
  const ushort_t* Ws = Sqkv + (size_t)branch * 3 * 262144;
  const float* scp = (branch == 0) ? qsc : ((branch == 1) ? ksc : vsc);
  const float* bip = (branch == 0) ? qbi : ((branch == 1) ? kbi : vbi);

  __shared__ alignas(16) ushort_t As[4][2][64][32];   // 32 KB, linear dest
  __shared__ alignas(16) u8 Bs8[4][256][32];          // 32 KB, linear dest

  const int tid  = threadIdx.x;
  const int lane = tid & 63;
  const int wave = tid >> 6;
  const int wrow = (wave >> 1) * 16;   // m strip (16 rows)
  const int wcol = (wave & 1) * 128;   // n half (128 cols)
  const int frow = lane & 15;
  const int fsl  = lane >> 4;          // 8-elem slot 0..3

  const u8* Bb0 = xsT8 + (size_t)b * N_DIM * C_DIM;

  // staging: 8 A-chunks (plane p = w>>2, 16-row group q = w&3) + 8 B-chunks
  // (32 n-rows each, cbx = w). Every wave: exactly 1 A + 1 B gload16.
  const int a0p = wave >> 2, a0q = wave & 3;
  const int arl = lane >> 2;                              // row within 16
  const int acl = (((lane & 3) ^ ((arl >> 1) & 3)) * 8);  // swizzled 16B slot (ushort units)
  const int brl = lane >> 1;                              // row within 32
  const int bcl = (((lane & 1) ^ ((brl >> 2) & 1) ^ ((brl >> 3) & 1)) * 16); // swizzled 16B half (bytes)
  const int cbx = wave;

#define K2_STAGE(s_) {                                                                     \
    const int ss_ = (s_);                                                                  \
    const int t_ = ss_ >> 4; const int kb_ = (ss_ & 15) * 32; const int bf_ = ss_ & 3;     \
    gload16(Ws + (size_t)a0p * 262144 + (size_t)(mloc + a0q * 16 + arl) * 512 + kb_ + acl, \
            &As[bf_][a0p][a0q * 16][0]);                                                   \
    gload16(Bb0 + (size_t)t_ * (B_DIM * N_DIM * C_DIM) + (size_t)(cbx * 32 + brl) * 512 + kb_ + bcl, \
            &Bs8[bf_][cbx * 32][0]);                                                       \
  }

  f32x4 acc[8];
  float vst[32];
#pragma unroll
  for (int i = 0; i < 32; i++) vst[i] = 0.f;
#pragma unroll
  for (int j = 0; j < 8; j++) acc[j] = (f32x4){0.f, 0.f, 0.f, 0.f};

  // preload BN scale/bias for this thread's 4 c-rows (constant across t)
  const int crow0 = (lane >> 4) * 4;
  const int cn    = lane & 15;
  float sc4[4], bi4[4];
#pragma unroll
  for (int r = 0; r < 4; r++) {
    int c = mloc + wrow + crow0 + r;
    sc4[r] = scp[c]; bi4[r] = bip[c];
  }

  K2_STAGE(0);
  K2_STAGE(1);

  for (int s = 0; s < 64; s++) {
    const int cur = s & 3;
    if (s < 62) K2_STAGE(s + 2);   // issue depth-2 prefetch into buf (s+2)&3

    // wait for stage s only; keep 2 stages (4 loads) in flight.
    if (s < 62)      asm volatile("s_waitcnt vmcnt(4)" ::: "memory");
    else if (s == 62) asm volatile("s_waitcnt vmcnt(2)" ::: "memory");
    else              asm volatile("s_waitcnt vmcnt(0)" ::: "memory");
    __builtin_amdgcn_s_barrier();
    __builtin_amdgcn_sched_barrier(0);

    bf16x8 af[2];
    const int ar = wrow + frow;
    const int asw = (fsl ^ ((ar >> 1) & 3)) * 8;   // matches source pre-swizzle
#pragma unroll
    for (int p = 0; p < 2; p++) af[p] = *(const bf16x8*)&As[cur][p][ar][asw];

#pragma unroll
    for (int j = 0; j < 8; j++) {
      const int row = wcol + j * 16 + frow;
      const int bx  = ((row >> 2) ^ (row >> 3)) & 1;
      const int bsw = (((fsl >> 1) ^ bx) << 4) + ((fsl & 1) << 3); // matches source pre-swizzle
      uint2 raw = *(const uint2*)&Bs8[cur][row][bsw];
      union { bf16x8 v; unsigned int u[4]; } bu;
      bu.u[0] = __builtin_amdgcn_perm(0u, raw.x, 0x05010400u) * 0x3F80u;
      bu.u[1] = __builtin_amdgcn_perm(0u, raw.x, 0x07030602u) * 0x3F80u;
      bu.u[2] = __builtin_amdgcn_perm(0u, raw.y, 0x05010400u) * 0x3F80u;
      bu.u[3] = __builtin_amdgcn_perm(0u, raw.y, 0x07030602u) * 0x3F80u;
#pragma unroll
      for (int p = 0; p < 2; p++)
        acc[j] = __builtin_amdgcn_mfma_f32_16x16x32_bf16(af[p], bu.v, acc[j], 0, 0, 0);
    }

    if ((s & 15) == 15) {
      // epilogue for t = s>>4 (stores enter vmcnt FIFO; the next counted
      // wait retires them - slightly conservative, still correct)
      const int t = s >> 4;
      const size_t tb = (size_t)t * B_DIM + b;
      if (branch < 2) {
        u8* dst = (branch == 0) ? qs8 : ks8;
#pragma unroll
        for (int r = 0; r < 4; r++) {
          const int c = mloc + wrow + crow0 + r;
#pragma unroll
          for (int j = 0; j < 8; j++) {
            const int n = wcol + j * 16 + cn;
            float y = acc[j][r] * sc4[r] + bi4[r];
            const int vi = j * 4 + r;
            float v = vst[vi];
            v = v + (y - v) * 0.5f;
            bool sp = (v >= 1.0f);
            vst[vi] = sp ? 0.f : v;
            dst[(tb * C_DIM + c) * N_DIM + n] = sp ? (u8)1 : (u8)0;
          }
        }
      } else {
        const int hv = mloc >> 6;
        const int d0 = wrow + crow0;
#pragma unroll
        for (int j = 0; j < 8; j++) {
          const int n = wcol + j * 16 + cn;
          float ov[4];
          u8 sv[4];
#pragma unroll
          for (int r = 0; r < 4; r++) {
            float y = acc[j][r] * sc4[r] + bi4[r];
            const int vi = j * 4 + r;
            float v = vst[vi];
            v = v + (y - v) * 0.5f;
            bool sp = (v >= 1.0f);
            vst[vi] = sp ? 0.f : v;
            ov[r] = sp ? 1.0f : 0.0f;
            sv[r] = sp ? (u8)1 : (u8)0;
          }
          const size_t vbase = ((tb * 8 + hv) * N_DIM + n) * 64 + d0;
          *(float4*)(vout + vbase) = make_float4(ov[0], ov[1], ov[2], ov[3]);
          *(uchar4*)(vs8 + vbase)  = make_uchar4(sv[0], sv[1], sv[2], sv[3]);
        }
      }
#pragma unroll
      for (int j = 0; j < 8; j++) acc[j] = (f32x4){0.f, 0.f, 0.f, 0.f};
    }
  }
#undef K2_STAGE
}

// ---------------------------------------------------------------------------
// K3: attn[ch,b,h,d,e] = (1/16) * sum_{t,n} k[d,(t,n)] * v[(t,n),e]
// V read as u8 spikes (vs8 from K2) - straight uint4 staging, no converts.
// ---------------------------------------------------------------------------
__global__ __launch_bounds__(256) void k3_attn(
    const u8* __restrict__ ks8, const u8* __restrict__ vs8,
    float* __restrict__ attn)
{
  const int h  = blockIdx.x;
  const int b  = blockIdx.y;
  const int ch = blockIdx.z;
  __shared__ u8 KtT[64][80];
  __shared__ u8 Vt[64][80];
  const int tid = threadIdx.x;
  const int d0 = (tid >> 4) * 4;
  const int e0 = (tid & 15) * 4;
  float a[16];
#pragma unroll
  for (int i = 0; i < 16; i++) a[i] = 0.f;

  for (int tt = 0; tt < 2; tt++) {
    int t = ch * 2 + tt;
    for (int n0 = 0; n0 < 256; n0 += 64) {
      __syncthreads();
      {
        int d  = tid >> 2;
        int s0 = (tid & 3) * 16;
        union { uint4 u; u8 bvec[16]; } kb;
        kb.u = *(const uint4*)(ks8 + ((((size_t)t * B_DIM + b) * C_DIM) + h * 64 + d) * N_DIM + n0 + s0);
#pragma unroll
        for (int i = 0; i < 16; i++) KtT[s0 + i][d] = kb.bvec[i];
      }
      {
        const u8* vb = vs8 + ((((size_t)t * B_DIM + b) * 8 + h) * N_DIM + n0) * 64;
        int row = tid >> 2;
        int eo  = (tid & 3) * 16;
        *(uint4*)&Vt[row][eo] = *(const uint4*)(vb + (size_t)row * 64 + eo);
      }
      __syncthreads();
      for (int s = 0; s < 64; s++) {
        uchar4 kb = *(const uchar4*)&KtT[s][d0];
        float kv[4] = { (float)kb.x, (float)kb.y, (float)kb.z, (float)kb.w };
        uchar4 vr = *(const uchar4*)&Vt[s][e0];
        float vv[4] = { (float)vr.x, (float)vr.y, (float)vr.z, (float)vr.w };
#pragma unroll
        for (int i = 0; i < 4; i++)
#pragma unroll
          for (int j = 0; j < 4; j++) a[i * 4 + j] += kv[i] * vv[j];
      }
    }
  }
  float* ap = attn + ((((size_t)ch * B_DIM + b) * 8 + h) * 64 + d0) * 64 + e0;
#pragma unroll
  for (int i = 0; i < 4; i++)
#pragma unroll
    for (int j = 0; j < 4; j++)
      ap[i * 64 + j] = a[i * 4 + j] * 0.0625f;
}

// ---------------------------------------------------------------------------
// K4: out[e,n] = sum_d attn[d,e]*q[d,n], attn-LIF(0.5) -> x2sT8[t,b,n,c] u8.
// n-chunk split across grid.z for 4x parallelism; vst[16] per thread.
// ---------------------------------------------------------------------------
__global__ __launch_bounds__(256) void k4_out_lif(
    const u8* __restrict__ qs8, const float* __restrict__ attn,
    u8* __restrict__ x2sT8)
{
  const int h  = blockIdx.x;
  const int b  = blockIdx.y;
  const int nc = blockIdx.z;   // 0..3
  __shared__ float At[64][68];
  __shared__ u8 Qt[64][80];
  const int tid = threadIdx.x;
  const int e0 = (tid >> 4) * 4;
  const int n0 = (tid & 15) * 4;
  float vst[16];
#pragma unroll
  for (int i = 0; i < 16; i++) vst[i] = 0.f;

  for (int t = 0; t < T_DIM; t++) {
    if ((t & 1) == 0) {
      __syncthreads();
      const float* ap = attn + ((((size_t)(t >> 1) * B_DIM + b) * 8) + h) * 4096;
      int dr = tid >> 2;
      int co = (tid & 3) * 16;
#pragma unroll
      for (int u = 0; u < 4; u++)
        *(float4*)&At[dr][co + u * 4] = *(const float4*)(ap + dr * 64 + co + u * 4);
    }
    __syncthreads();
    {
      int d  = tid >> 2;
      int so = (tid & 3) * 16;
      *(uint4*)&Qt[d][so] =
        *(const uint4*)(qs8 + ((((size_t)t * B_DIM + b) * C_DIM) + h * 64 + d) * N_DIM + nc * 64 + so);
    }
    __syncthreads();
    float acc[16];
#pragma unroll
    for (int i = 0; i < 16; i++) acc[i] = 0.f;
    for (int d = 0; d < 64; d++) {
      float4 av = *(const float4*)&At[d][e0];
      float avv[4] = { av.x, av.y, av.z, av.w };
      uchar4 qr = *(const uchar4*)&Qt[d][n0];
      float qv[4] = { (float)qr.x, (float)qr.y, (float)qr.z, (float)qr.w };
#pragma unroll
      for (int i = 0; i < 4; i++)
#pragma unroll
        for (int j = 0; j < 4; j++) acc[i * 4 + j] += avv[i] * qv[j];
    }
#pragma unroll
    for (int j = 0; j < 4; j++) {
      u8 sv[4];
#pragma unroll
      for (int i = 0; i < 4; i++) {
        int vi = i * 4 + j;
        float y = acc[i * 4 + j];
        float nv = vst[vi] + (y - vst[vi]) * 0.5f;
        bool s = (nv >= 0.5f);
        vst[vi] = s ? 0.f : nv;
        sv[i] = s ? (u8)1 : (u8)0;
      }
      int n = nc * 64 + n0 + j;
      u8* op = x2sT8 + ((((size_t)t * B_DIM + b) * N_DIM) + n) * C_DIM + h * 64 + e0;
      *(uchar4*)op = make_uchar4(sv[0], sv[1], sv[2], sv[3]);
    }
  }
}

// ---------------------------------------------------------------------------
// K5: proj conv1x1 (+bp)*scale+bias + residual -> out0 fp32. Same engine as
// K2: 2 planes, depth-2 counted-vmcnt, 4 LDS buffers (64 KB), uniform
// 2 loads/wave. Grid (tb, mt): XCD = tb%8.
// ---------------------------------------------------------------------------
__global__ __launch_bounds__(512, 4) void k5_proj(
    const u8* __restrict__ x2sT8, const ushort_t* __restrict__ Sp,
    const float* __restrict__ bp, const float* __restrict__ psc,
    const float* __restrict__ pbi,
    const float* __restrict__ x, float* __restrict__ out0)
{
  const int tb = blockIdx.x;   // 0..127 (fast dim -> XCD = tb%8)
  const int mt = blockIdx.y;   // 0..7
  const int mloc = mt * 64;

  __shared__ alignas(16) ushort_t As[4][2][64][32];
  __shared__ alignas(16) u8 Bs8[4][256][32];

  const int tid  = threadIdx.x;
  const int lane = tid & 63;
  const int wave = tid >> 6;
  const int wrow = (wave >> 1) * 16;
  const int wcol = (wave & 1) * 128;
  const int frow = lane & 15;
  const int fsl  = lane >> 4;

  const u8* Bb = x2sT8 + (size_t)tb * N_DIM * C_DIM;

  const int a0p = wave >> 2, a0q = wave & 3;
  const int arl = lane >> 2;
  const int acl = (((lane & 3) ^ ((arl >> 1) & 3)) * 8);
  const int brl = lane >> 1;
  const int bcl = (((lane & 1) ^ ((brl >> 2) & 1) ^ ((brl >> 3) & 1)) * 16);
  const int cbx = wave;

#define K5_STAGE(s_) {                                                                     \
    const int ss_ = (s_); const int kb_ = ss_ * 32; const int bf_ = ss_ & 3;               \
    gload16(Sp + (size_t)a0p * 262144 + (size_t)(mloc + a0q * 16 + arl) * 512 + kb_ + acl, \
            &As[bf_][a0p][a0q * 16][0]);                                                   \
    gload16(Bb + (size_t)(cbx * 32 + brl) * 512 + kb_ + bcl, &Bs8[bf_][cbx * 32][0]);      \
  }

  f32x4 acc[8];
#pragma unroll
  for (int j = 0; j < 8; j++) acc[j] = (f32x4){0.f, 0.f, 0.f, 0.f};

  K5_STAGE(0);
  K5_STAGE(1);

  for (int s = 0; s < 16; s++) {
    const int cur = s & 3;
    if (s < 14) K5_STAGE(s + 2);

    if (s < 14)       asm volatile("s_waitcnt vmcnt(4)" ::: "memory");
    else if (s == 14) asm volatile("s_waitcnt vmcnt(2)" ::: "memory");
    else              asm volatile("s_waitcnt vmcnt(0)" ::: "memory");
    __builtin_amdgcn_s_barrier();
    __builtin_amdgcn_sched_barrier(0);

    bf16x8 af[2];
    const int ar = wrow + frow;
    const int asw = (fsl ^ ((ar >> 1) & 3)) * 8;
#pragma unroll
    for (int p = 0; p < 2; p++) af[p] = *(const bf16x8*)&As[cur][p][ar][asw];

#pragma unroll
    for (int j = 0; j < 8; j++) {
      const int row = wcol + j * 16 + frow;
      const int bx  = ((row >> 2) ^ (row >> 3)) & 1;
      const int bsw = (((fsl >> 1) ^ bx) << 4) + ((fsl & 1) << 3);
      uint2 raw = *(const uint2*)&Bs8[cur][row][bsw];
      union { bf16x8 v; unsigned int u[4]; } bu;
      bu.u[0] = __builtin_amdgcn_perm(0u, raw.x, 0x05010400u) * 0x3F80u;
      bu.u[1] = __builtin_amdgcn_perm(0u, raw.x, 0x07030602u) * 0x3F80u;
      bu.u[2] = __builtin_amdgcn_perm(0u, raw.y, 0x05010400u) * 0x3F80u;
      bu.u[3] = __builtin_amdgcn_perm(0u, raw.y, 0x07030602u) * 0x3F80u;
#pragma unroll
      for (int p = 0; p < 2; p++)
        acc[j] = __builtin_amdgcn_mfma_f32_16x16x32_bf16(af[p], bu.v, acc[j], 0, 0, 0);
    }
  }

  const int crow0 = (lane >> 4) * 4;
  const int cn    = lane & 15;
#pragma unroll
  for (int r = 0; r < 4; r++) {
    const int c = mloc + wrow + crow0 + r;
    const float scf = psc[c];
    const float bif = pbi[c];
    const float bpf = bp[c];
#pragma unroll
    for (int j = 0; j < 8; j++) {
      const int n = wcol + j * 16 + cn;
      const size_t idx = ((size_t)tb * C_DIM + c) * N_DIM + n;
      out0[idx] = (acc[j][r] + bpf) * scf + bif + x[idx];
    }
  }
#undef K5_STAGE
}

// ---------------------------------------------------------------------------
// fp32 problem. d_out = 33,554,432 floats: out0 [0,64MB), out1 [64MB,128MB).
// Scratch in out0 byte region (dead until K5 overwrites it):
//   o0+0    xsT8 16MB [K1->K2]  (aliased by attn 8MB [K3->K4])
//   o0+16M  qs8 16MB [K2->K4] ; o0+32M ks8 16MB [K2->K3]
//   o0+48M  Sqkv split 4.5MB [K0->K2] ; o0+56M vs8 8MB [K2->K3]
// d_ws: x2sT8 16MB [K4->K5]; +16M Sp split 1.5MB [K0->K5].
// ---------------------------------------------------------------------------
extern "C" void kernel_launch(void* const* d_in, const int* in_sizes, int n_in,
                              void* d_out, int out_size, void* d_ws, size_t ws_size,
                              hipStream_t stream) {
  const float* x   = (const float*)d_in[0];
  const float* Wq  = (const float*)d_in[1];
  const float* qsc = (const float*)d_in[2];
  const float* qbi = (const float*)d_in[3];
  const float* Wk  = (const float*)d_in[4];
  const float* ksc = (const float*)d_in[5];
  const float* kbi = (const float*)d_in[6];
  const float* Wv  = (const float*)d_in[7];
  const float* vsc = (const float*)d_in[8];
  const float* vbi = (const float*)d_in[9];
  const float* Wp  = (const float*)d_in[10];
  const float* bp  = (const float*)d_in[11];
  const float* psc = (const float*)d_in[12];
  const float* pbi = (const float*)d_in[13];

  float* out0 = (float*)d_out;
  float* out1 = out0 + 16777216;

  const size_t M16 = 16u * 1024u * 1024u;
  char* o0 = (char*)d_out;
  char* ws = (char*)d_ws;

  u8*       xsT8  = (u8*)(o0);
  u8*       qs8   = (u8*)(o0 + M16);
  u8*       ks8   = (u8*)(o0 + 2 * M16);
  ushort_t* Sqkv  = (ushort_t*)(o0 + 3 * M16);
  u8*       vs8   = (u8*)(o0 + 3 * M16 + 8u * 1024u * 1024u);
  float*    attn  = (float*)(o0);
  u8*       x2sT8 = (u8*)(ws);
  ushort_t* Sp    = (ushort_t*)(ws + M16);

  hipLaunchKernelGGL(k0_split,        dim3(512),        dim3(256), 0, stream,
                     Wq, Wk, Wv, Wp, Sqkv, Sp);
  hipLaunchKernelGGL(k1_shortcut_lif, dim3(4, 8, 32),   dim3(256), 0, stream, x, xsT8);
  hipLaunchKernelGGL(k2_qkv,          dim3(24, 32),     dim3(512), 0, stream,
                     xsT8, Sqkv, qsc, qbi, ksc, kbi, vsc, vbi, qs8, ks8, out1, vs8);
  hipLaunchKernelGGL(k3_attn,         dim3(8, 32, 2),   dim3(256), 0, stream, ks8, vs8, attn);
  hipLaunchKernelGGL(k4_out_lif,      dim3(8, 32, 4),   dim3(256), 0, stream, qs8, attn, x2sT8);
  hipLaunchKernelGGL(k5_proj,         dim3(128, 8),     dim3(512), 0, stream,
                     x2sT8, Sp, bp, psc, pbi, x, out0);
}

// Round 7
// 430.088 us; speedup vs baseline: 1.2170x; 1.0868x over previous
//
#include <hip/hip_runtime.h>

typedef unsigned short ushort_t;
typedef unsigned char u8;
typedef short bf16x8 __attribute__((ext_vector_type(8)));
typedef float f32x4 __attribute__((ext_vector_type(4)));

#define T_DIM 4
#define B_DIM 32
#define C_DIM 512
#define N_DIM 256

__device__ __forceinline__ float bf2f(ushort_t u) {
  union { unsigned int i; float f; } x;
  x.i = ((unsigned int)u) << 16;
  return x.f;
}
__device__ __forceinline__ ushort_t f2bf(float f) {
  unsigned int u = __float_as_uint(f);
  u = (u + 0x7FFFu + ((u >> 16) & 1u)) >> 16;
  return (ushort_t)u;
}

// async global->LDS DMA, 16B per lane, lane i lands at ldsbase + i*16
__device__ __forceinline__ void gload16(const void* g, void* l) {
  __builtin_amdgcn_global_load_lds(
      (const __attribute__((address_space(1))) unsigned int*)g,
      (__attribute__((address_space(3))) unsigned int*)l, 16, 0, 0);
}

// 0/1 spike bytes (2 per word, at bytes 0 and 2) -> 2 bf16 halfwords.
// operands < 2^24 so v_mul_u32_u24 (full-rate, literal-in-src0) is exact.
__device__ __forceinline__ unsigned int spike2bf(unsigned int w) {
  unsigned int r;
  asm("v_mul_u32_u24 %0, 0x3f80, %1" : "=v"(r) : "v"(w));
  return r;
}
__device__ __forceinline__ bf16x8 expand_spikes(uint2 raw) {
  union { bf16x8 v; unsigned int u[4]; } bu;
  bu.u[0] = spike2bf(__builtin_amdgcn_perm(0u, raw.x, 0x05010400u));
  bu.u[1] = spike2bf(__builtin_amdgcn_perm(0u, raw.x, 0x07030602u));
  bu.u[2] = spike2bf(__builtin_amdgcn_perm(0u, raw.y, 0x05010400u));
  bu.u[3] = spike2bf(__builtin_amdgcn_perm(0u, raw.y, 0x07030602u));
  return bu.v;
}

// ---------------------------------------------------------------------------
// K0: split fp32 weights into 3 bf16 planes (hi, mid, lo). W ~= hi+mid+lo.
// (K2/K5 consume only hi+mid.)
// ---------------------------------------------------------------------------
__global__ __launch_bounds__(256) void k0_split(
    const float* __restrict__ Wq, const float* __restrict__ Wk,
    const float* __restrict__ Wv, const float* __restrict__ Wp,
    ushort_t* __restrict__ Sqkv, ushort_t* __restrict__ Sp)
{
  int gid = blockIdx.x * 256 + threadIdx.x;   // [0, 131072)
  int w = gid >> 15;
  int off = (gid & 32767) * 8;
  const float* src = (w == 0) ? Wq : ((w == 1) ? Wk : ((w == 2) ? Wv : Wp));
  ushort_t* dst = (w < 3) ? (Sqkv + (size_t)w * 3 * 262144) : Sp;
  float wv[8];
  *(float4*)&wv[0] = *(const float4*)(src + off);
  *(float4*)&wv[4] = *(const float4*)(src + off + 4);
  ushort_t hi[8], mi[8], lo[8];
#pragma unroll
  for (int i = 0; i < 8; i++) {
    float f = wv[i];
    ushort_t h = f2bf(f);  float r  = f - bf2f(h);
    ushort_t m = f2bf(r);  float r2 = r - bf2f(m);
    ushort_t l = f2bf(r2);
    hi[i] = h; mi[i] = m; lo[i] = l;
  }
  *(uint4*)(dst + off)              = *(uint4*)&hi[0];
  *(uint4*)(dst + 262144 + off)     = *(uint4*)&mi[0];
  *(uint4*)(dst + 2 * 262144 + off) = *(uint4*)&lo[0];
}

// ---------------------------------------------------------------------------
// K1: shortcut LIF on x [T,B,C,N] (fp32) -> spikes transposed xsT8 [T,B,N,C] u8
// ---------------------------------------------------------------------------
__global__ __launch_bounds__(256) void k1_shortcut_lif(
    const float* __restrict__ x, u8* __restrict__ xsT8)
{
  const int n0 = blockIdx.x * 64;
  const int c0 = blockIdx.y * 64;
  const int b  = blockIdx.z;
  __shared__ u8 sm[64][80];
  const int tid = threadIdx.x;
  const int r  = tid >> 2;
  const int j0 = (tid & 3) * 16;
  float v[16];
#pragma unroll
  for (int i = 0; i < 16; i++) v[i] = 0.f;
  for (int t = 0; t < T_DIM; t++) {
    const float* xp = x + ((((size_t)t * B_DIM + b) * C_DIM) + c0 + r) * N_DIM + n0 + j0;
    float xv[16];
    *(float4*)&xv[0]  = *(const float4*)xp;
    *(float4*)&xv[4]  = *(const float4*)(xp + 4);
    *(float4*)&xv[8]  = *(const float4*)(xp + 8);
    *(float4*)&xv[12] = *(const float4*)(xp + 12);
    __syncthreads();
#pragma unroll
    for (int i = 0; i < 16; i++) {
      float nv = v[i] + (xv[i] - v[i]) * 0.5f;
      bool s = (nv >= 1.0f);
      v[i] = s ? 0.f : nv;
      sm[j0 + i][r] = s ? (u8)1 : (u8)0;
    }
    __syncthreads();
    union { uint4 u; u8 b[16]; } ov;
#pragma unroll
    for (int i = 0; i < 16; i++) ov.b[i] = sm[r][j0 + i];
    u8* op = xsT8 + ((((size_t)t * B_DIM + b) * N_DIM) + n0 + r) * C_DIM + c0 + j0;
    *(uint4*)op = ov.u;
  }
}

// ---------------------------------------------------------------------------
// K2: QKV conv1x1 + BN + LIF. 512 threads (8 waves), 64m x 256n block tile,
// wave tile 16m x 128n (acc[8]). TWO bf16 weight planes (hi+mid).
// Depth-2 counted-vmcnt pipeline: 4 rotating LDS buffers, 1 s_barrier/step,
// steady s_waitcnt vmcnt(4). Uniform 2 gload16/wave/stage.
// Outputs:
//    q -> qs8T[t,b,n,c] u8 (transposed, uchar4 stores)  [K4 B-operand]
//    k -> ks8 [t,b,c,n] u8                              [K3 A-operand]
//    v -> vout[t,b,h,n,d] fp32 0/1 (out1)  +  vs8T[t,b,h,e,n] u8 [K3 B-op]
// ---------------------------------------------------------------------------
__global__ __launch_bounds__(512, 4) void k2_qkv(
    const u8* __restrict__ xsT8, const ushort_t* __restrict__ Sqkv,
    const float* __restrict__ qsc, const float* __restrict__ qbi,
    const float* __restrict__ ksc, const float* __restrict__ kbi,
    const float* __restrict__ vsc, const float* __restrict__ vbi,
    u8* __restrict__ qs8T, u8* __restrict__ ks8, float* __restrict__ vout,
    u8* __restrict__ vs8T)
{
  const int lin = blockIdx.x + blockIdx.y * 24;        // 0..767
  const int b   = (lin & 7) | (((lin >> 3) & 3) << 3); // XCD = lin%8 = b%8
  const int mt  = lin >> 5;                            // 0..23
  const int branch = mt >> 3;         // 0=q 1=k 2=v
  const int mloc = (mt & 7) * 64;     // within branch's 512
  const ushort_t* Ws = Sqkv + (size_t)branch * 3 * 262144;
  const float* scp = (branch == 0) ? qsc : ((branch == 1) ? ksc : vsc);
  const float* bip = (branch == 0) ? qbi : ((branch == 1) ? kbi : vbi);

  __shared__ alignas(16) ushort_t As[4][2][64][32];   // 32 KB, linear dest
  __shared__ alignas(16) u8 Bs8[4][256][32];          // 32 KB, linear dest

  const int tid  = threadIdx.x;
  const int lane = tid & 63;
  const int wave = tid >> 6;
  const int wrow = (wave >> 1) * 16;   // m strip (16 rows)
  const int wcol = (wave & 1) * 128;   // n half (128 cols)
  const int frow = lane & 15;
  const int fsl  = lane >> 4;          // 8-elem slot 0..3

  const u8* Bb0 = xsT8 + (size_t)b * N_DIM * C_DIM;

  const int a0p = wave >> 2, a0q = wave & 3;
  const int arl = lane >> 2;                              // row within 16
  const int acl = (((lane & 3) ^ ((arl >> 1) & 3)) * 8);  // swizzled 16B slot (ushort units)
  const int brl = lane >> 1;                              // row within 32
  const int bcl = (((lane & 1) ^ ((brl >> 2) & 1) ^ ((brl >> 3) & 1)) * 16); // swizzled 16B half (bytes)
  const int cbx = wave;

#define K2_STAGE(s_) {                                                                     \
    const int ss_ = (s_);                                                                  \
    const int t_ = ss_ >> 4; const int kb_ = (ss_ & 15) * 32; const int bf_ = ss_ & 3;     \
    gload16(Ws + (size_t)a0p * 262144 + (size_t)(mloc + a0q * 16 + arl) * 512 + kb_ + acl, \
            &As[bf_][a0p][a0q * 16][0]);                                                   \
    gload16(Bb0 + (size_t)t_ * (B_DIM * N_DIM * C_DIM) + (size_t)(cbx * 32 + brl) * 512 + kb_ + bcl, \
            &Bs8[bf_][cbx * 32][0]);                                                       \
  }

  f32x4 acc[8];
  float vst[32];
#pragma unroll
  for (int i = 0; i < 32; i++) vst[i] = 0.f;
#pragma unroll
  for (int j = 0; j < 8; j++) acc[j] = (f32x4){0.f, 0.f, 0.f, 0.f};

  const int crow0 = (lane >> 4) * 4;
  const int cn    = lane & 15;
  float sc4[4], bi4[4];
#pragma unroll
  for (int r = 0; r < 4; r++) {
    int c = mloc + wrow + crow0 + r;
    sc4[r] = scp[c]; bi4[r] = bip[c];
  }

  K2_STAGE(0);
  K2_STAGE(1);

  for (int s = 0; s < 64; s++) {
    const int cur = s & 3;
    if (s < 62) K2_STAGE(s + 2);

    if (s < 62)       asm volatile("s_waitcnt vmcnt(4)" ::: "memory");
    else if (s == 62) asm volatile("s_waitcnt vmcnt(2)" ::: "memory");
    else              asm volatile("s_waitcnt vmcnt(0)" ::: "memory");
    __builtin_amdgcn_s_barrier();
    __builtin_amdgcn_sched_barrier(0);

    bf16x8 af[2];
    const int ar = wrow + frow;
    const int asw = (fsl ^ ((ar >> 1) & 3)) * 8;
#pragma unroll
    for (int p = 0; p < 2; p++) af[p] = *(const bf16x8*)&As[cur][p][ar][asw];

#pragma unroll
    for (int j = 0; j < 8; j++) {
      const int row = wcol + j * 16 + frow;
      const int bx  = ((row >> 2) ^ (row >> 3)) & 1;
      const int bsw = (((fsl >> 1) ^ bx) << 4) + ((fsl & 1) << 3);
      bf16x8 bv = expand_spikes(*(const uint2*)&Bs8[cur][row][bsw]);
#pragma unroll
      for (int p = 0; p < 2; p++)
        acc[j] = __builtin_amdgcn_mfma_f32_16x16x32_bf16(af[p], bv, acc[j], 0, 0, 0);
    }

    if ((s & 15) == 15) {
      const int t = s >> 4;
      const size_t tb = (size_t)t * B_DIM + b;
      if (branch == 0) {
#pragma unroll
        for (int j = 0; j < 8; j++) {
          const int n = wcol + j * 16 + cn;
          u8 sv[4];
#pragma unroll
          for (int r = 0; r < 4; r++) {
            float y = acc[j][r] * sc4[r] + bi4[r];
            const int vi = j * 4 + r;
            float v = vst[vi];
            v = v + (y - v) * 0.5f;
            bool sp = (v >= 1.0f);
            vst[vi] = sp ? 0.f : v;
            sv[r] = sp ? (u8)1 : (u8)0;
          }
          *(uchar4*)(qs8T + (tb * N_DIM + n) * C_DIM + mloc + wrow + crow0) =
              make_uchar4(sv[0], sv[1], sv[2], sv[3]);
        }
      } else if (branch == 1) {
#pragma unroll
        for (int r = 0; r < 4; r++) {
          const int c = mloc + wrow + crow0 + r;
#pragma unroll
          for (int j = 0; j < 8; j++) {
            const int n = wcol + j * 16 + cn;
            float y = acc[j][r] * sc4[r] + bi4[r];
            const int vi = j * 4 + r;
            float v = vst[vi];
            v = v + (y - v) * 0.5f;
            bool sp = (v >= 1.0f);
            vst[vi] = sp ? 0.f : v;
            ks8[(tb * C_DIM + c) * N_DIM + n] = sp ? (u8)1 : (u8)0;
          }
        }
      } else {
        const int hv = mloc >> 6;
        const int d0 = wrow + crow0;
#pragma unroll
        for (int j = 0; j < 8; j++) {
          const int n = wcol + j * 16 + cn;
          float ov[4];
          u8 sv[4];
#pragma unroll
          for (int r = 0; r < 4; r++) {
            float y = acc[j][r] * sc4[r] + bi4[r];
            const int vi = j * 4 + r;
            float v = vst[vi];
            v = v + (y - v) * 0.5f;
            bool sp = (v >= 1.0f);
            vst[vi] = sp ? 0.f : v;
            ov[r] = sp ? 1.0f : 0.0f;
            sv[r] = sp ? (u8)1 : (u8)0;
          }
          *(float4*)(vout + ((tb * 8 + hv) * N_DIM + n) * 64 + d0) =
              make_float4(ov[0], ov[1], ov[2], ov[3]);
#pragma unroll
          for (int r = 0; r < 4; r++)
            vs8T[((tb * 8 + hv) * 64 + d0 + r) * N_DIM + n] = sv[r];
        }
      }
#pragma unroll
      for (int j = 0; j < 8; j++) acc[j] = (f32x4){0.f, 0.f, 0.f, 0.f};
    }
  }
#undef K2_STAGE
}

// ---------------------------------------------------------------------------
// K3 (MFMA): attn[d,e] = (1/16) * sum_{t,n} K[d,tn] * V[tn,e].
// A = ks8 rows [d][n] u8; B = vs8T rows [e][n] u8 (V^T). 4 waves, K=512
// (16 k-steps of 32), depth-2 counted-vmcnt (1 gload16/wave/stage).
// Output: attnT2 = attn^T split into EXACT 2-plane bf16 (counts/16 < 2^11),
// k-step-blocked layout [blk][p][ks2][e][32d] so K4's A-reads are the
// standard 64B-row swizzled geometry.
// ---------------------------------------------------------------------------
__global__ __launch_bounds__(256) void k3_attn(
    const u8* __restrict__ ks8, const u8* __restrict__ vs8T,
    ushort_t* __restrict__ attnT2)
{
  const int h  = blockIdx.x;
  const int b  = blockIdx.y;
  const int ch = blockIdx.z;
  __shared__ alignas(16) u8 Ks[4][64][32];
  __shared__ alignas(16) u8 Vs[4][64][32];
  const int tid  = threadIdx.x;
  const int lane = tid & 63;
  const int wave = tid >> 6;        // 0..3
  const int wrow = wave * 16;       // d strip
  const int frow = lane & 15;
  const int fsl  = lane >> 4;
  const int brl  = lane >> 1;
  const int bcl  = (((lane & 1) ^ ((brl >> 2) & 1) ^ ((brl >> 3) & 1)) * 16);

#define K3_STAGE(s_) {                                                                     \
    const int ss_ = (s_);                                                                  \
    const int t_ = ch * 2 + (ss_ >> 3); const int kb_ = (ss_ & 7) * 32; const int bf_ = ss_ & 3; \
    if (wave < 2)                                                                          \
      gload16(ks8 + ((((size_t)t_ * B_DIM + b) * C_DIM) + h * 64 + wave * 32 + brl) * N_DIM + kb_ + bcl, \
              &Ks[bf_][wave * 32][0]);                                                     \
    else                                                                                   \
      gload16(vs8T + ((((size_t)t_ * B_DIM + b) * 8 + h) * 64 + (wave - 2) * 32 + brl) * N_DIM + kb_ + bcl, \
              &Vs[bf_][(wave - 2) * 32][0]);                                               \
  }

  f32x4 acc[4];
#pragma unroll
  for (int i = 0; i < 4; i++) acc[i] = (f32x4){0.f, 0.f, 0.f, 0.f};

  K3_STAGE(0);
  K3_STAGE(1);

  for (int s = 0; s < 16; s++) {
    const int cur = s & 3;
    if (s < 14) K3_STAGE(s + 2);

    if (s < 14)       asm volatile("s_waitcnt vmcnt(2)" ::: "memory");
    else if (s == 14) asm volatile("s_waitcnt vmcnt(1)" ::: "memory");
    else              asm volatile("s_waitcnt vmcnt(0)" ::: "memory");
    __builtin_amdgcn_s_barrier();
    __builtin_amdgcn_sched_barrier(0);

    const int arow = wrow + frow;
    const int axx  = ((arow >> 2) ^ (arow >> 3)) & 1;
    const int asw  = (((fsl >> 1) ^ axx) << 4) + ((fsl & 1) << 3);
    bf16x8 af = expand_spikes(*(const uint2*)&Ks[cur][arow][asw]);

#pragma unroll
    for (int nt = 0; nt < 4; nt++) {
      const int row = nt * 16 + frow;
      const int bx  = ((row >> 2) ^ (row >> 3)) & 1;
      const int bsw = (((fsl >> 1) ^ bx) << 4) + ((fsl & 1) << 3);
      bf16x8 bv = expand_spikes(*(const uint2*)&Vs[cur][row][bsw]);
      acc[nt] = __builtin_amdgcn_mfma_f32_16x16x32_bf16(af, bv, acc[nt], 0, 0, 0);
    }
  }

  // epilogue: C[d][e] -> attnT2[e][d] as 2 exact bf16 planes.
  const int cn    = lane & 15;
  const int crow0 = (lane >> 4) * 4;
  const int d     = wrow + crow0;       // 4 consecutive via r
  const int ks2   = d >> 5;
  const int dl    = d & 31;
  const size_t blk = ((size_t)(ch * B_DIM + b) * 8 + h);
#pragma unroll
  for (int nt = 0; nt < 4; nt++) {
    const int e = nt * 16 + cn;
    union { ushort_t sv[4]; uint2 u; } H, M;
#pragma unroll
    for (int r = 0; r < 4; r++) {
      float a = acc[nt][r] * 0.0625f;
      ushort_t hi = f2bf(a);
      float m = a - bf2f(hi);
      H.sv[r] = hi;
      M.sv[r] = f2bf(m);
    }
    *(uint2*)(attnT2 + ((blk * 2 + 0) * 2 + ks2) * 2048 + (size_t)e * 32 + dl) = H.u;
    *(uint2*)(attnT2 + ((blk * 2 + 1) * 2 + ks2) * 2048 + (size_t)e * 32 + dl) = M.u;
  }
#undef K3_STAGE
}

// ---------------------------------------------------------------------------
// K4 (MFMA): out[e,n] = sum_d attnT[e,d] * q[d,n]; LIF(0.5) over t in regs;
// -> x2sT8[t,b,n,c] u8 (uchar4 along c). A = attnT2 planes (both ch staged
// in prologue, 32 KB); B = qs8T rows [n][c] u8, staged per k-step (m97-style
// depth-1). 4 waves, wave tile 16e x 128n, acc[8], vst[32]. nc splits N.
// Exact vs scalar version (fp32 MFMA of integers/16 < 2^15).
// ---------------------------------------------------------------------------
__global__ __launch_bounds__(256) void k4_out_lif(
    const u8* __restrict__ qs8T, const ushort_t* __restrict__ attnT2,
    u8* __restrict__ x2sT8)
{
  const int h  = blockIdx.x;
  const int b  = blockIdx.y;
  const int nc = blockIdx.z;   // 0..1
  __shared__ alignas(16) ushort_t As[2][2][2][64][32];  // [ch][p][ks][e][32d] 32 KB
  __shared__ alignas(16) u8 Bs[2][128][32];             // 8 KB
  const int tid  = threadIdx.x;
  const int lane = tid & 63;
  const int wave = tid >> 6;        // 0..3
  const int wrow = wave * 16;       // e strip
  const int frow = lane & 15;
  const int fsl  = lane >> 4;
  const int arl  = lane >> 2;
  const int acl  = (((lane & 3) ^ ((arl >> 1) & 3)) * 8);
  const int brl  = lane >> 1;
  const int bcl  = (((lane & 1) ^ ((brl >> 2) & 1) ^ ((brl >> 3) & 1)) * 16);

#define K4_STAGEB(s_) {                                                                    \
    const int ss_ = (s_); const int t_ = ss_ >> 1; const int ks_ = ss_ & 1;                \
    gload16(qs8T + (((size_t)t_ * B_DIM + b) * N_DIM + nc * 128 + wave * 32 + brl) * C_DIM \
                 + h * 64 + ks_ * 32 + bcl,                                                \
            &Bs[ss_ & 1][wave * 32][0]);                                                   \
  }

  // prologue: stage A for BOTH ch (8 chunks/wave) + B(0).
#pragma unroll
  for (int i = 0; i < 8; i++) {
    const int c  = wave * 8 + i;
    const int chb = c >> 4, c4 = c & 15;
    const int p = c4 >> 3, ks = (c4 >> 2) & 1, g = c4 & 3;
    const size_t blk = ((size_t)(chb * B_DIM + b) * 8 + h);
    gload16(attnT2 + (((blk * 2 + p) * 2 + ks) * 64 + g * 16 + arl) * 32 + acl,
            &As[chb][p][ks][g * 16][0]);
  }
  K4_STAGEB(0);
  asm volatile("s_waitcnt vmcnt(0)" ::: "memory");
  __builtin_amdgcn_s_barrier();
  __builtin_amdgcn_sched_barrier(0);

  f32x4 acc[8];
  float vst[32];
#pragma unroll
  for (int i = 0; i < 32; i++) vst[i] = 0.f;

  const int cn    = lane & 15;
  const int crow0 = (lane >> 4) * 4;

  for (int sg = 0; sg < 8; sg++) {
    const int cur = sg & 1;
    if (sg < 7) K4_STAGEB(sg + 1);

    const int chb = sg >> 2, ks = sg & 1;
    if (ks == 0) {
#pragma unroll
      for (int j = 0; j < 8; j++) acc[j] = (f32x4){0.f, 0.f, 0.f, 0.f};
    }

    bf16x8 af[2];
    const int ar = wrow + frow;
    const int asw = (fsl ^ ((ar >> 1) & 3)) * 8;
#pragma unroll
    for (int p = 0; p < 2; p++) af[p] = *(const bf16x8*)&As[chb][p][ks][ar][asw];

#pragma unroll
    for (int j = 0; j < 8; j++) {
      const int row = j * 16 + frow;
      const int bx  = ((row >> 2) ^ (row >> 3)) & 1;
      const int bsw = (((fsl >> 1) ^ bx) << 4) + ((fsl & 1) << 3);
      bf16x8 bv = expand_spikes(*(const uint2*)&Bs[cur][row][bsw]);
#pragma unroll
      for (int p = 0; p < 2; p++)
        acc[j] = __builtin_amdgcn_mfma_f32_16x16x32_bf16(af[p], bv, acc[j], 0, 0, 0);
    }

    if (ks == 1) {
      const int t = sg >> 1;
      const size_t tb = (size_t)t * B_DIM + b;
#pragma unroll
      for (int j = 0; j < 8; j++) {
        const int n = nc * 128 + j * 16 + cn;
        u8 sv[4];
#pragma unroll
        for (int r = 0; r < 4; r++) {
          const int vi = j * 4 + r;
          float y = acc[j][r];
          float nv = vst[vi] + (y - vst[vi]) * 0.5f;
          bool sp = (nv >= 0.5f);
          vst[vi] = sp ? 0.f : nv;
          sv[r] = sp ? (u8)1 : (u8)0;
        }
        *(uchar4*)(x2sT8 + (tb * N_DIM + n) * C_DIM + h * 64 + wrow + crow0) =
            make_uchar4(sv[0], sv[1], sv[2], sv[3]);
      }
    }

    asm volatile("s_waitcnt vmcnt(0)" ::: "memory");
    __builtin_amdgcn_s_barrier();
    __builtin_amdgcn_sched_barrier(0);
  }
#undef K4_STAGEB
}

// ---------------------------------------------------------------------------
// K5: proj conv1x1 (+bp)*scale+bias + residual -> out0 fp32. k2 engine:
// 2 planes, depth-2 counted-vmcnt, 4 LDS buffers, uniform 2 loads/wave.
// Grid (tb, mt): XCD = tb%8.
// ---------------------------------------------------------------------------
__global__ __launch_bounds__(512, 4) void k5_proj(
    const u8* __restrict__ x2sT8, const ushort_t* __restrict__ Sp,
    const float* __restrict__ bp, const float* __restrict__ psc,
    const float* __restrict__ pbi,
    const float* __restrict__ x, float* __restrict__ out0)
{
  const int tb = blockIdx.x;   // 0..127 (fast dim -> XCD = tb%8)
  const int mt = blockIdx.y;   // 0..7
  const int mloc = mt * 64;

  __shared__ alignas(16) ushort_t As[4][2][64][32];
  __shared__ alignas(16) u8 Bs8[4][256][32];

  const int tid  = threadIdx.x;
  const int lane = tid & 63;
  const int wave = tid >> 6;
  const int wrow = (wave >> 1) * 16;
  const int wcol = (wave & 1) * 128;
  const int frow = lane & 15;
  const int fsl  = lane >> 4;

  const u8* Bb = x2sT8 + (size_t)tb * N_DIM * C_DIM;

  const int a0p = wave >> 2, a0q = wave & 3;
  const int arl = lane >> 2;
  const int acl = (((lane & 3) ^ ((arl >> 1) & 3)) * 8);
  const int brl = lane >> 1;
  const int bcl = (((lane & 1) ^ ((brl >> 2) & 1) ^ ((brl >> 3) & 1)) * 16);
  const int cbx = wave;

#define K5_STAGE(s_) {                                                                     \
    const int ss_ = (s_); const int kb_ = ss_ * 32; const int bf_ = ss_ & 3;               \
    gload16(Sp + (size_t)a0p * 262144 + (size_t)(mloc + a0q * 16 + arl) * 512 + kb_ + acl, \
            &As[bf_][a0p][a0q * 16][0]);                                                   \
    gload16(Bb + (size_t)(cbx * 32 + brl) * 512 + kb_ + bcl, &Bs8[bf_][cbx * 32][0]);      \
  }

  f32x4 acc[8];
#pragma unroll
  for (int j = 0; j < 8; j++) acc[j] = (f32x4){0.f, 0.f, 0.f, 0.f};

  K5_STAGE(0);
  K5_STAGE(1);

  for (int s = 0; s < 16; s++) {
    const int cur = s & 3;
    if (s < 14) K5_STAGE(s + 2);

    if (s < 14)       asm volatile("s_waitcnt vmcnt(4)" ::: "memory");
    else if (s == 14) asm volatile("s_waitcnt vmcnt(2)" ::: "memory");
    else              asm volatile("s_waitcnt vmcnt(0)" ::: "memory");
    __builtin_amdgcn_s_barrier();
    __builtin_amdgcn_sched_barrier(0);

    bf16x8 af[2];
    const int ar = wrow + frow;
    const int asw = (fsl ^ ((ar >> 1) & 3)) * 8;
#pragma unroll
    for (int p = 0; p < 2; p++) af[p] = *(const bf16x8*)&As[cur][p][ar][asw];

#pragma unroll
    for (int j = 0; j < 8; j++) {
      const int row = wcol + j * 16 + frow;
      const int bx  = ((row >> 2) ^ (row >> 3)) & 1;
      const int bsw = (((fsl >> 1) ^ bx) << 4) + ((fsl & 1) << 3);
      bf16x8 bv = expand_spikes(*(const uint2*)&Bs8[cur][row][bsw]);
#pragma unroll
      for (int p = 0; p < 2; p++)
        acc[j] = __builtin_amdgcn_mfma_f32_16x16x32_bf16(af[p], bv, acc[j], 0, 0, 0);
    }
  }

  const int crow0 = (lane >> 4) * 4;
  const int cn    = lane & 15;
#pragma unroll
  for (int r = 0; r < 4; r++) {
    const int c = mloc + wrow + crow0 + r;
    const float scf = psc[c];
    const float bif = pbi[c];
    const float bpf = bp[c];
#pragma unroll
    for (int j = 0; j < 8; j++) {
      const int n = wcol + j * 16 + cn;
      const size_t idx = ((size_t)tb * C_DIM + c) * N_DIM + n;
      out0[idx] = (acc[j][r] + bpf) * scf + bif + x[idx];
    }
  }
#undef K5_STAGE
}

// ---------------------------------------------------------------------------
// Memory map (race-free):
// d_out (128 MB): out0 bytes [0,64M) used as scratch until K5:
//   [0,16M)  xsT8 [K1->K2]   ; attnT2 8MB reuses [0,8M) [K3->K4] (xsT8 dead)
//   [16,32M) qs8T [K2->K4]
//   [32,48M) ks8  [K2->K3]
//   [48,64M) vs8T [K2->K3]
// out1 bytes [64,128M) = vout (fp32 v output, written by K2).
// d_ws (17.5 MB used):
//   [0,16M)   x2sT8 [K4->K5]; Sqkv 4.5MB aliases [0,4.5M) [K0->K2]
//             (safe: K2 reads Sqkv before K4 writes x2sT8)
//   [16,17.5M) Sp [K0->K5]
// ---------------------------------------------------------------------------
extern "C" void kernel_launch(void* const* d_in, const int* in_sizes, int n_in,
                              void* d_out, int out_size, void* d_ws, size_t ws_size,
                              hipStream_t stream) {
  const float* x   = (const float*)d_in[0];
  const float* Wq  = (const float*)d_in[1];
  const float* qsc = (const float*)d_in[2];
  const float* qbi = (const float*)d_in[3];
  const float* Wk  = (const float*)d_in[4];
  const float* ksc = (const float*)d_in[5];
  const float* kbi = (const float*)d_in[6];
  const float* Wv  = (const float*)d_in[7];
  const float* vsc = (const float*)d_in[8];
  const float* vbi = (const float*)d_in[9];
  const float* Wp  = (const float*)d_in[10];
  const float* bp  = (const float*)d_in[11];
  const float* psc = (const float*)d_in[12];
  const float* pbi = (const float*)d_in[13];

  float* out0 = (float*)d_out;
  float* out1 = out0 + 16777216;

  const size_t M16 = 16u * 1024u * 1024u;
  char* o0 = (char*)d_out;
  char* ws = (char*)d_ws;

  u8*       xsT8   = (u8*)(o0);
  ushort_t* attnT2 = (ushort_t*)(o0);
  u8*       qs8T   = (u8*)(o0 + M16);
  u8*       ks8    = (u8*)(o0 + 2 * M16);
  u8*       vs8T   = (u8*)(o0 + 3 * M16);
  u8*       x2sT8  = (u8*)(ws);
  ushort_t* Sqkv   = (ushort_t*)(ws);
  ushort_t* Sp     = (ushort_t*)(ws + M16);

  hipLaunchKernelGGL(k0_split,        dim3(512),        dim3(256), 0, stream,
                     Wq, Wk, Wv, Wp, Sqkv, Sp);
  hipLaunchKernelGGL(k1_shortcut_lif, dim3(4, 8, 32),   dim3(256), 0, stream, x, xsT8);
  hipLaunchKernelGGL(k2_qkv,          dim3(24, 32),     dim3(512), 0, stream,
                     xsT8, Sqkv, qsc, qbi, ksc, kbi, vsc, vbi, qs8T, ks8, out1, vs8T);
  hipLaunchKernelGGL(k3_attn,         dim3(8, 32, 2),   dim3(256), 0, stream,
                     ks8, vs8T, attnT2);
  hipLaunchKernelGGL(k4_out_lif,      dim3(8, 32, 2),   dim3(256), 0, stream,
                     qs8T, attnT2, x2sT8);
  hipLaunchKernelGGL(k5_proj,         dim3(128, 8),     dim3(512), 0, stream,
                     x2sT8, Sp, bp, psc, pbi, x, out0);
}